// Round 5
// baseline (194.815 us; speedup 1.0000x reference)
//
#include <hip/hip_runtime.h>

// Problem constants
#define B_SZ   8
#define S_LEN  1024
#define D_MOD  256
#define NHEADS 8
#define M_ROWS (B_SZ * S_LEN)   // 8192
#define LOG2E  1.4426950408889634f
#define QSCALE_LOG2E 0.2550352766751165f   // (1/sqrt(32)) * log2(e)

typedef _Float16 f16x8 __attribute__((ext_vector_type(8)));
typedef _Float16 f16x4 __attribute__((ext_vector_type(4)));
typedef float    f32x4 __attribute__((ext_vector_type(4)));

// 8 contiguous fp32 -> f16x8
__device__ inline f16x8 cvt8(const float* p) {
    f32x4 a = *(const f32x4*)p, b = *(const f32x4*)(p + 4);
    f16x8 r;
#pragma unroll
    for (int j = 0; j < 4; ++j) { r[j] = (_Float16)a[j]; r[4 + j] = (_Float16)b[j]; }
    return r;
}

// ---------------------------------------------------------------------------
// Prep: (a) blocks 0..31: transpose+convert 4 fp32 W mats -> fp16 Wt[n][k].
//       (b) blocks 32..409: bias C-init table
//           tab[h][dy31][e][lane] = float4 with
//           val[reg] = rel[(dy31*63 + 16e + l16 - quad*4 - reg + 15)*8 + h]*LOG2E
// ---------------------------------------------------------------------------
__global__ __launch_bounds__(256)
void prep_kernel(const float* __restrict__ Wq, const float* __restrict__ Wk,
                 const float* __restrict__ Wv, const float* __restrict__ Wo,
                 const float* __restrict__ rel,
                 _Float16* __restrict__ wt, float* __restrict__ tab) {
    if (blockIdx.x < 32) {
        const int mi = blockIdx.x >> 3;
        const int k0 = (blockIdx.x & 7) << 5;
        const float* W = (mi == 0) ? Wq : (mi == 1) ? Wk : (mi == 2) ? Wv : Wo;
        const int n = threadIdx.x;
        const float* src = W + (size_t)k0 * 256 + n;
        _Float16* dst = wt + (size_t)mi * 65536 + (size_t)n * 256 + k0;
#pragma unroll
        for (int g = 0; g < 4; ++g) {
            f16x8 o;
#pragma unroll
            for (int j = 0; j < 8; ++j) o[j] = (_Float16)src[(size_t)(g * 8 + j) * 256];
            *(f16x8*)(dst + g * 8) = o;
        }
        return;
    }
    const int flat = (blockIdx.x - 32) * 256 + threadIdx.x;   // 0..96767
    const int lane = flat & 63;
    const int t1   = flat >> 6;        // 0..1511
    const int e    = t1 % 3;
    const int t2   = t1 / 3;           // 0..503
    const int dy31 = t2 % 63;
    const int h    = t2 / 63;
    const int quad = lane >> 4, l16 = lane & 15;
    f32x4 v;
#pragma unroll
    for (int reg = 0; reg < 4; ++reg) {
        const int idx = 16 * e + l16 - quad * 4 - reg + 15;
        v[reg] = rel[(size_t)(dy31 * 63 + idx) * NHEADS + h] * LOG2E;
    }
    *(f32x4*)(tab + (size_t)flat * 4) = v;
}

// ---------------------------------------------------------------------------
// Zero-LDS, zero-barrier GEMM: out[M,256] = (A @ W + bias) * scale, Wt[n][k].
// Both MFMA operands are direct contiguous b128 global loads (A row-major
// k-contiguous; Wt n-major k-contiguous). 64x64 block tile, wave = 32x32
// quadrant, 8 unrolled K=32 steps — pure load+MFMA stream, compiler-pipelined.
// ---------------------------------------------------------------------------
__global__ __launch_bounds__(256)
void gemm_qkv_kernel(const float* __restrict__ in_q, const float* __restrict__ in_kv,
                     const _Float16* __restrict__ wt,
                     const float* __restrict__ bq, const float* __restrict__ bk,
                     const float* __restrict__ bv,
                     _Float16* __restrict__ qh, _Float16* __restrict__ kh,
                     _Float16* __restrict__ vt) {
    const int tid  = threadIdx.x;
    const int w    = tid >> 6;
    const int lane = tid & 63;
    const int quad = lane >> 4;
    const int l16  = lane & 15;
    const int m0 = blockIdx.x * 64, n0 = blockIdx.y * 64, z = blockIdx.z;
    const int mq = (w & 1) * 32, nq = (w >> 1) * 32;

    const float* A = z ? in_kv : in_q;
    const float* a0p = A + (size_t)(m0 + mq + l16) * 256;
    const float* a1p = a0p + 16 * 256;
    const _Float16* wb = wt + (size_t)z * 65536;
    const _Float16* b0p = wb + (size_t)(n0 + nq + l16) * 256;
    const _Float16* b1p = b0p + 16 * 256;

    f32x4 acc[2][2];
#pragma unroll
    for (int i = 0; i < 2; ++i)
#pragma unroll
        for (int j = 0; j < 2; ++j) acc[i][j] = (f32x4){0.f, 0.f, 0.f, 0.f};

#pragma unroll
    for (int kk = 0; kk < 8; ++kk) {
        const int k8 = kk * 32 + quad * 8;
        f16x8 fa0 = cvt8(a0p + k8);
        f16x8 fa1 = cvt8(a1p + k8);
        f16x8 fb0 = *(const f16x8*)(b0p + k8);
        f16x8 fb1 = *(const f16x8*)(b1p + k8);
        acc[0][0] = __builtin_amdgcn_mfma_f32_16x16x32_f16(fa0, fb0, acc[0][0], 0, 0, 0);
        acc[0][1] = __builtin_amdgcn_mfma_f32_16x16x32_f16(fa0, fb1, acc[0][1], 0, 0, 0);
        acc[1][0] = __builtin_amdgcn_mfma_f32_16x16x32_f16(fa1, fb0, acc[1][0], 0, 0, 0);
        acc[1][1] = __builtin_amdgcn_mfma_f32_16x16x32_f16(fa1, fb1, acc[1][1], 0, 0, 0);
    }

    if (z == 2) {
        // V: transposed write vt[((b*8+head)*32+hd)*1024 + s]
        const int b8 = (m0 >> 10) * 8;
#pragma unroll
        for (int nh = 0; nh < 2; ++nh) {
            const int col = n0 + nq + nh * 16 + l16;
            const float bvv = bv[col];
#pragma unroll
            for (int mh = 0; mh < 2; ++mh) {
                const int row0 = (m0 & 1023) + mq + mh * 16 + quad * 4;
                f16x4 pk;
#pragma unroll
                for (int r = 0; r < 4; ++r) pk[r] = (_Float16)(acc[mh][nh][r] + bvv);
                *(f16x4*)(vt + ((size_t)(b8 + (col >> 5)) * 32 + (col & 31)) * 1024 + row0) = pk;
            }
        }
    } else {
        _Float16* out = z ? kh : qh;
        const float* bias = z ? bk : bq;
        const float scale = z ? 1.0f : QSCALE_LOG2E;
#pragma unroll
        for (int nh = 0; nh < 2; ++nh) {
            const int col = n0 + nq + nh * 16 + l16;
            const float bvv = bias[col];
#pragma unroll
            for (int mh = 0; mh < 2; ++mh) {
#pragma unroll
                for (int r = 0; r < 4; ++r) {
                    const int row = m0 + mq + mh * 16 + quad * 4 + r;
                    out[(size_t)row * 256 + col] = (_Float16)((acc[mh][nh][r] + bvv) * scale);
                }
            }
        }
    }
}

// Output GEMM: same zero-LDS structure, fp16 A (xh), fp32 out.
__global__ __launch_bounds__(256)
void gemm_out_kernel(const _Float16* __restrict__ X, const _Float16* __restrict__ wt3,
                     const float* __restrict__ bo, float* __restrict__ out) {
    const int tid  = threadIdx.x;
    const int w    = tid >> 6;
    const int lane = tid & 63;
    const int quad = lane >> 4;
    const int l16  = lane & 15;
    const int m0 = blockIdx.x * 64, n0 = blockIdx.y * 64;
    const int mq = (w & 1) * 32, nq = (w >> 1) * 32;

    const _Float16* a0p = X + (size_t)(m0 + mq + l16) * 256;
    const _Float16* a1p = a0p + 16 * 256;
    const _Float16* b0p = wt3 + (size_t)(n0 + nq + l16) * 256;
    const _Float16* b1p = b0p + 16 * 256;

    f32x4 acc[2][2];
#pragma unroll
    for (int i = 0; i < 2; ++i)
#pragma unroll
        for (int j = 0; j < 2; ++j) acc[i][j] = (f32x4){0.f, 0.f, 0.f, 0.f};

#pragma unroll
    for (int kk = 0; kk < 8; ++kk) {
        const int k8 = kk * 32 + quad * 8;
        f16x8 fa0 = *(const f16x8*)(a0p + k8);
        f16x8 fa1 = *(const f16x8*)(a1p + k8);
        f16x8 fb0 = *(const f16x8*)(b0p + k8);
        f16x8 fb1 = *(const f16x8*)(b1p + k8);
        acc[0][0] = __builtin_amdgcn_mfma_f32_16x16x32_f16(fa0, fb0, acc[0][0], 0, 0, 0);
        acc[0][1] = __builtin_amdgcn_mfma_f32_16x16x32_f16(fa0, fb1, acc[0][1], 0, 0, 0);
        acc[1][0] = __builtin_amdgcn_mfma_f32_16x16x32_f16(fa1, fb0, acc[1][0], 0, 0, 0);
        acc[1][1] = __builtin_amdgcn_mfma_f32_16x16x32_f16(fa1, fb1, acc[1][1], 0, 0, 0);
    }

#pragma unroll
    for (int nh = 0; nh < 2; ++nh) {
        const int col = n0 + nq + nh * 16 + l16;
        const float bvv = bo[col];
#pragma unroll
        for (int mh = 0; mh < 2; ++mh) {
#pragma unroll
            for (int r = 0; r < 4; ++r) {
                const int row = m0 + mq + mh * 16 + quad * 4 + r;
                out[(size_t)row * 256 + col] = acc[mh][nh][r] + bvv;
            }
        }
    }
}

// ---------------------------------------------------------------------------
// Flash attention, transposed dataflow, NO split-K, NO barriers.
// grid 1024 (XCD-swizzled): (qc 0..15, bh 0..63). 4 waves, wave = 16 q-rows.
// Per KV tile of 32 keys:
//   S^T[32k x 16q] = MFMA(A=K-frags x2, B=Q-frag, C=bias-tab f32x4)  [2 MFMA]
//   exp2 -> P^T as 2x ds_write_b64 -> 1x ds_read_b128 (wave-private)
//   O^T[32hd x 16q] = MFMA(A=V^T-frags x2, B=P) + ones row-sum       [3 MFMA]
// 16 waves/CU (50% occ). Normalized fp16 xh out via rcp(ones-sum).
// ---------------------------------------------------------------------------
__global__ __launch_bounds__(256)
void attn_kernel(const _Float16* __restrict__ q, const _Float16* __restrict__ k,
                 const _Float16* __restrict__ vt, const float* __restrict__ tab,
                 _Float16* __restrict__ xh) {
    __shared__ __align__(16) _Float16 Ps[4][16][40];

    const int tid  = threadIdx.x;
    const int w    = tid >> 6;
    const int lane = tid & 63;
    const int quad = lane >> 4;
    const int l16  = lane & 15;

    const int n     = blockIdx.x;
    const int xcd   = n & 7;
    const int local = n >> 3;          // 0..127
    const int bh    = xcd * 8 + (local & 7);
    const int qc    = local >> 3;      // 0..15
    const int b = bh >> 3, h = bh & 7;
    const int qrow_base = qc * 64 + w * 16;
    const int yq = qrow_base >> 5;
    const int e0 = (w & 1) + 1;        // C-init tab slice for keys 0-15
    const int e1 = (w & 1);            // for keys 16-31

    // Q B-frag: B[k=hd][n=q], lane l16 = q-row, 8 contiguous hd
    const f16x8 qf =
        *(const f16x8*)(q + ((size_t)(b * S_LEN + qrow_base + l16)) * D_MOD + h * 32 + quad * 8);
    const _Float16* kp = k + ((size_t)(b * S_LEN + l16)) * D_MOD + h * 32 + quad * 8;
    const _Float16* vp = vt + ((size_t)(bh * 32 + l16)) * S_LEN + quad * 8;
    const float* tb = tab + (size_t)h * 63 * 3 * 256 + lane * 4;

    f16x8 ones;
#pragma unroll
    for (int j = 0; j < 8; ++j) ones[j] = (_Float16)1.0f;

    f32x4 o0 = {0.f,0.f,0.f,0.f}, o1 = {0.f,0.f,0.f,0.f}, ol = {0.f,0.f,0.f,0.f};

    // prologue: tile-0 operands
    f16x8 kf0 = *(const f16x8*)(kp);
    f16x8 kf1 = *(const f16x8*)(kp + 16 * D_MOD);
    f16x8 vf0 = *(const f16x8*)(vp);
    f16x8 vf1 = *(const f16x8*)(vp + 16 * S_LEN);
    f32x4 c0 = *(const f32x4*)(tb + (size_t)((yq + 31) * 3 + e0) * 256);
    f32x4 c1 = *(const f32x4*)(tb + (size_t)((yq + 31) * 3 + e1) * 256);

    for (int kt = 0; kt < 32; ++kt) {
        const bool more = (kt < 31);
        f16x8 nk0, nk1, nv0, nv1;
        f32x4 nc0, nc1;
        if (more) {
            const _Float16* kq = kp + (size_t)(kt + 1) * 32 * D_MOD;
            nk0 = *(const f16x8*)(kq);
            nk1 = *(const f16x8*)(kq + 16 * D_MOD);
            const _Float16* vq = vp + (kt + 1) * 32;
            nv0 = *(const f16x8*)(vq);
            nv1 = *(const f16x8*)(vq + 16 * S_LEN);
            const int dy31n = yq + 30 - kt;
            nc0 = *(const f32x4*)(tb + (size_t)(dy31n * 3 + e0) * 256);
            nc1 = *(const f32x4*)(tb + (size_t)(dy31n * 3 + e1) * 256);
        }

        // S^T with bias C-init (rows = keys, cols = q)
        f32x4 s0 = __builtin_amdgcn_mfma_f32_16x16x32_f16(kf0, qf, c0, 0, 0, 0);
        f32x4 s1 = __builtin_amdgcn_mfma_f32_16x16x32_f16(kf1, qf, c1, 0, 0, 0);

        f16x4 p;
#pragma unroll
        for (int r = 0; r < 4; ++r) p[r] = (_Float16)__builtin_amdgcn_exp2f(s0[r]);
        *(f16x4*)(&Ps[w][l16][quad * 4]) = p;
#pragma unroll
        for (int r = 0; r < 4; ++r) p[r] = (_Float16)__builtin_amdgcn_exp2f(s1[r]);
        *(f16x4*)(&Ps[w][l16][16 + quad * 4]) = p;

        // P B-frag: lane l16 = q-col, 8 contiguous k
        const f16x8 pf = *(const f16x8*)(&Ps[w][l16][quad * 8]);
        o0 = __builtin_amdgcn_mfma_f32_16x16x32_f16(vf0, pf, o0, 0, 0, 0);
        o1 = __builtin_amdgcn_mfma_f32_16x16x32_f16(vf1, pf, o1, 0, 0, 0);
        ol = __builtin_amdgcn_mfma_f32_16x16x32_f16(ones, pf, ol, 0, 0, 0);

        if (more) { kf0 = nk0; kf1 = nk1; vf0 = nv0; vf1 = nv1; c0 = nc0; c1 = nc1; }
    }

    // epilogue: all regs of ol carry this q-col's sum; normalize, store fp16
    const float inv = __builtin_amdgcn_rcpf(ol[0]);
    f16x4 w0, w1;
#pragma unroll
    for (int r = 0; r < 4; ++r) {
        w0[r] = (_Float16)(o0[r] * inv);
        w1[r] = (_Float16)(o1[r] * inv);
    }
    _Float16* op = xh + ((size_t)(b * S_LEN + qrow_base + l16)) * D_MOD + h * 32 + quad * 4;
    *(f16x4*)(op)      = w0;   // hd = quad*4+r
    *(f16x4*)(op + 16) = w1;   // hd = 16+quad*4+r
}

// ---------------------------------------------------------------------------
extern "C" void kernel_launch(void* const* d_in, const int* in_sizes, int n_in,
                              void* d_out, int out_size, void* d_ws, size_t ws_size,
                              hipStream_t stream) {
    const float* in_q  = (const float*)d_in[0];
    const float* in_kv = (const float*)d_in[1];
    const float* Wq    = (const float*)d_in[2];
    const float* bq    = (const float*)d_in[3];
    const float* Wk    = (const float*)d_in[4];
    const float* bk    = (const float*)d_in[5];
    const float* Wv    = (const float*)d_in[6];
    const float* bv    = (const float*)d_in[7];
    const float* rel   = (const float*)d_in[8];
    const float* Wo    = (const float*)d_in[9];
    const float* bo    = (const float*)d_in[10];
    float* out = (float*)d_out;

    char* wsb = (char*)d_ws;
    _Float16* qh  = (_Float16*)(wsb);                        // 4 MB
    _Float16* kh  = (_Float16*)(wsb + (size_t)4  * 1048576); // 4 MB
    _Float16* vt  = (_Float16*)(wsb + (size_t)8  * 1048576); // 4 MB (V^T per (b,h))
    _Float16* xh  = (_Float16*)(wsb + (size_t)12 * 1048576); // 4 MB
    _Float16* wt  = (_Float16*)(wsb + (size_t)16 * 1048576); // 512 KB
    float*    tab = (float*)   (wsb + (size_t)17 * 1048576); // ~1.48 MB

    const dim3 blk(256);

    prep_kernel<<<dim3(410), blk, 0, stream>>>(Wq, Wk, Wv, Wo, rel, wt, tab);
    gemm_qkv_kernel<<<dim3(M_ROWS / 64, 4, 3), blk, 0, stream>>>(
        in_q, in_kv, wt, bq, bk, bv, qh, kh, vt);
    attn_kernel<<<dim3(1024), blk, 0, stream>>>(qh, kh, vt, tab, xh);
    gemm_out_kernel<<<dim3(M_ROWS / 64, 4), blk, 0, stream>>>(xh, wt + (size_t)3 * 65536, bo, out);
}

// Round 6
// 124.060 us; speedup vs baseline: 1.5703x; 1.5703x over previous
//
#include <hip/hip_runtime.h>

// Problem constants
#define B_SZ   8
#define S_LEN  1024
#define D_MOD  256
#define NHEADS 8
#define M_ROWS 8192
#define LOG2E  1.4426950408889634f
#define QSCALE_LOG2E 0.2550352766751165f   // (1/sqrt(32)) * log2(e)

typedef _Float16 f16x8 __attribute__((ext_vector_type(8)));
typedef _Float16 f16x4 __attribute__((ext_vector_type(4)));
typedef float    f32x4 __attribute__((ext_vector_type(4)));

// ---------------------------------------------------------------------------
// prep: blocks 0..31  : pack 4 fp32 W mats -> fragment-ordered fp16 wtp.
//        wtp[(mat*16+n16)*8+kk][lane][8] : val = W[kk*32 + (lane>>4)*8 + j]
//                                              [n16*16 + (lane&15)]
//       blocks 32..94 : bias C-init table (LDS-staged rel rows, coalesced out)
//        tab[((h*63+dy31)*3+e)*256 + lane*4 + r]
//          = rel[(dy31*63 + 16e + l16 - quad*4 - r + 15)*8 + h] * LOG2E
// ---------------------------------------------------------------------------
__global__ __launch_bounds__(256)
void prep_kernel(const float* __restrict__ Wq, const float* __restrict__ Wk,
                 const float* __restrict__ Wv, const float* __restrict__ Wo,
                 const float* __restrict__ rel,
                 _Float16* __restrict__ wtp, float* __restrict__ tab) {
    if (blockIdx.x < 32) {
        __shared__ _Float16 Wl[32 * 264];
        const int mi = blockIdx.x >> 3;
        const int k0 = (blockIdx.x & 7) << 5;
        const float* W = (mi == 0) ? Wq : (mi == 1) ? Wk : (mi == 2) ? Wv : Wo;
        // stage 32 k-rows x 256 n-cols, coalesced
        {
            const int r  = threadIdx.x >> 3;
            const int c4 = (threadIdx.x & 7) * 4;
            const float* src = W + (size_t)(k0 + r) * 256 + c4;
#pragma unroll
            for (int g = 0; g < 8; ++g) {
                f32x4 v = *(const f32x4*)(src + g * 32);
                f16x4 o;
#pragma unroll
                for (int j = 0; j < 4; ++j) o[j] = (_Float16)v[j];
                *(f16x4*)(&Wl[r * 264 + c4 + g * 32]) = o;
            }
        }
        __syncthreads();
        // emit fragment-packed wtp (kk = k0>>5 fixed for this block)
        const int n16 = threadIdx.x >> 4;
        const int l16 = threadIdx.x & 15;
        const int kk  = k0 >> 5;
#pragma unroll
        for (int quad = 0; quad < 4; ++quad) {
            f16x8 v;
#pragma unroll
            for (int j = 0; j < 8; ++j) v[j] = Wl[(quad * 8 + j) * 264 + n16 * 16 + l16];
            *(f16x8*)(wtp + (((size_t)(mi * 16 + n16) * 8 + kk) << 9) + (quad * 16 + l16) * 8) = v;
        }
        return;
    }
    // tab build: one block per dy31
    __shared__ float rl[63 * 8];
    const int dy31 = blockIdx.x - 32;
    for (int f = threadIdx.x; f < 504; f += 256) rl[f] = rel[(size_t)dy31 * 504 + f];
    __syncthreads();
    const int h  = threadIdx.x >> 5;
    const int r5 = threadIdx.x & 31;
#pragma unroll
    for (int c = 0; c < 6; ++c) {
        const int oi   = r5 * 6 + c;       // 0..191
        const int e    = oi >> 6;
        const int lane = oi & 63;
        const int quad = lane >> 4, l16 = lane & 15;
        f32x4 v;
#pragma unroll
        for (int reg = 0; reg < 4; ++reg) {
            const int idx = 16 * e + l16 - quad * 4 - reg + 15;   // in [0,62]
            v[reg] = rl[idx * 8 + h] * LOG2E;
        }
        *(f32x4*)(tab + (((size_t)(h * 63 + dy31) * 3 + e) << 8) + lane * 4) = v;
    }
}

// ---------------------------------------------------------------------------
// QKV GEMM. A staged to LDS (coalesced); B streamed from frag-packed wtp.
// z=0: Q (swapped operands -> D=Q^T, packed qs epilogue, scale folded).
// z=1: K (swapped -> packed ks) + V (normal -> packed vs), sharing the A tile.
// Packed layout: xs[((bh*32 + t)*2 + sub)*512 + lane*8]:
//   qs/ks: lane -> (row = t*32 + sub*16 + (lane&15), hd = (lane>>4)*8 + j)
//   vs:    lane -> (hd  = sub*16 + (lane&15),  key = t*32 + (lane>>4)*8 + j)
// ---------------------------------------------------------------------------
__global__ __launch_bounds__(256)
void gemm_qkv_kernel(const float* __restrict__ in_q, const float* __restrict__ in_kv,
                     const _Float16* __restrict__ wtp,
                     const float* __restrict__ bq, const float* __restrict__ bk,
                     const float* __restrict__ bv,
                     _Float16* __restrict__ qs, _Float16* __restrict__ ks,
                     _Float16* __restrict__ vs) {
    __shared__ __align__(16) _Float16 As[64 * 264];
    _Float16* Ta = As;                 // epilogue tile (Q or K): [act64][hd 72]
    _Float16* Tb = As + 64 * 72;       // epilogue tile V: [hd64][key 72]

    const int tid  = threadIdx.x;
    const int w    = tid >> 6;
    const int lane = tid & 63;
    const int quad = lane >> 4;
    const int l16  = lane & 15;
    const int m0 = blockIdx.x * 64, n0 = blockIdx.y * 64, z = blockIdx.z;
    const int b = m0 >> 10, mloc = m0 & 1023;

    // stage A tile 64x256 fp32 -> fp16 (16-line coalesced loads)
    {
        const int r  = tid >> 2;
        const int c4 = (tid & 3) * 4;
        const float* src = (z ? in_kv : in_q) + (size_t)(m0 + r) * 256 + c4;
        _Float16* dst = As + r * 264 + c4;
#pragma unroll
        for (int g = 0; g < 16; ++g) {
            f32x4 v = *(const f32x4*)(src + g * 16);
            f16x4 o;
#pragma unroll
            for (int j = 0; j < 4; ++j) o[j] = (_Float16)v[j];
            *(f16x4*)(dst + g * 16) = o;
        }
    }
    __syncthreads();

    const int n16base = (n0 >> 4) + (w >> 1) * 2;
    const int mA = z ? 1 : 0;
    const _Float16* wA0 = wtp + (((size_t)(mA * 16 + n16base + 0) * 8) << 9) + lane * 8;
    const _Float16* wA1 = wtp + (((size_t)(mA * 16 + n16base + 1) * 8) << 9) + lane * 8;
    const _Float16* wV0 = wtp + (((size_t)(2 * 16 + n16base + 0) * 8) << 9) + lane * 8;
    const _Float16* wV1 = wtp + (((size_t)(2 * 16 + n16base + 1) * 8) << 9) + lane * 8;
    const _Float16* arow0 = As + ((w & 1) * 32 + l16) * 264;
    const _Float16* arow1 = arow0 + 16 * 264;

    f32x4 accA[2][2], accV[2][2];
#pragma unroll
    for (int i = 0; i < 2; ++i)
#pragma unroll
        for (int j = 0; j < 2; ++j) {
            accA[i][j] = (f32x4){0.f, 0.f, 0.f, 0.f};
            accV[i][j] = (f32x4){0.f, 0.f, 0.f, 0.f};
        }

#pragma unroll
    for (int kk = 0; kk < 8; ++kk) {
        const int k8 = kk * 32 + quad * 8;
        f16x8 a0 = *(const f16x8*)(arow0 + k8);
        f16x8 a1 = *(const f16x8*)(arow1 + k8);
        f16x8 w0 = *(const f16x8*)(wA0 + kk * 512);
        f16x8 w1 = *(const f16x8*)(wA1 + kk * 512);
        // swapped: D[m=hd][n=act]
        accA[0][0] = __builtin_amdgcn_mfma_f32_16x16x32_f16(w0, a0, accA[0][0], 0, 0, 0);
        accA[0][1] = __builtin_amdgcn_mfma_f32_16x16x32_f16(w0, a1, accA[0][1], 0, 0, 0);
        accA[1][0] = __builtin_amdgcn_mfma_f32_16x16x32_f16(w1, a0, accA[1][0], 0, 0, 0);
        accA[1][1] = __builtin_amdgcn_mfma_f32_16x16x32_f16(w1, a1, accA[1][1], 0, 0, 0);
        if (z == 1) {
            f16x8 v0 = *(const f16x8*)(wV0 + kk * 512);
            f16x8 v1 = *(const f16x8*)(wV1 + kk * 512);
            // normal: D[m=key][n=hd]
            accV[0][0] = __builtin_amdgcn_mfma_f32_16x16x32_f16(a0, v0, accV[0][0], 0, 0, 0);
            accV[0][1] = __builtin_amdgcn_mfma_f32_16x16x32_f16(a0, v1, accV[0][1], 0, 0, 0);
            accV[1][0] = __builtin_amdgcn_mfma_f32_16x16x32_f16(a1, v0, accV[1][0], 0, 0, 0);
            accV[1][1] = __builtin_amdgcn_mfma_f32_16x16x32_f16(a1, v1, accV[1][1], 0, 0, 0);
        }
    }
    __syncthreads();   // As reuse as Ta/Tb

    // ---- epilogue: bias + LDS transpose round-trip -> packed stores ----
    {
        const float* biasA = z ? bk : bq;
        const float  sc    = z ? 1.0f : QSCALE_LOG2E;
#pragma unroll
        for (int i = 0; i < 2; ++i) {
            f32x4 b4 = *(const f32x4*)(biasA + n0 + (w >> 1) * 32 + i * 16 + quad * 4);
#pragma unroll
            for (int jj = 0; jj < 2; ++jj) {
                f16x4 pk;
#pragma unroll
                for (int r = 0; r < 4; ++r) pk[r] = (_Float16)((accA[i][jj][r] + b4[r]) * sc);
                *(f16x4*)(Ta + ((w & 1) * 32 + jj * 16 + l16) * 72 +
                               (w >> 1) * 32 + i * 16 + quad * 4) = pk;
            }
        }
        if (z == 1) {
#pragma unroll
            for (int i = 0; i < 2; ++i) {
                const float bvv = bv[n0 + (w >> 1) * 32 + i * 16 + l16];
#pragma unroll
                for (int jj = 0; jj < 2; ++jj) {
                    f16x4 pk;
#pragma unroll
                    for (int r = 0; r < 4; ++r) pk[r] = (_Float16)(accV[jj][i][r] + bvv);
                    *(f16x4*)(Tb + ((w >> 1) * 32 + i * 16 + l16) * 72 +
                                   (w & 1) * 32 + jj * 16 + quad * 4) = pk;
                }
            }
        }
    }
    __syncthreads();
    {
        const int l16c = tid & 15, qdc = (tid >> 4) & 3;
        const int tile0 = mloc >> 5;
#pragma unroll
        for (int c2i = 0; c2i < 2; ++c2i) {
            const int c2 = w * 2 + c2i;
            const int s2 = c2 >> 2, sub = (c2 >> 1) & 1, hs = c2 & 1;
            const int bh = b * 8 + (n0 >> 5) + hs;
            const size_t dbase = (((size_t)(bh * 32 + tile0 + s2) * 2 + sub) << 9) + lane * 8;
            f16x8 va = *(const f16x8*)(Ta + (s2 * 32 + sub * 16 + l16c) * 72 +
                                            hs * 32 + qdc * 8);
            *(f16x8*)((z ? ks : qs) + dbase) = va;
            if (z == 1) {
                f16x8 vb = *(const f16x8*)(Tb + (hs * 32 + sub * 16 + l16c) * 72 +
                                                s2 * 32 + qdc * 8);
                *(f16x8*)(vs + dbase) = vb;
            }
        }
    }
}

// ---------------------------------------------------------------------------
// Output GEMM: A = xh (row-major fp16) staged to LDS; B = wtp[mat 3] stream.
// ---------------------------------------------------------------------------
__global__ __launch_bounds__(256)
void gemm_out_kernel(const _Float16* __restrict__ xh, const _Float16* __restrict__ wtp,
                     const float* __restrict__ bo, float* __restrict__ out) {
    __shared__ __align__(16) _Float16 As[64 * 264];
    const int tid  = threadIdx.x;
    const int w    = tid >> 6;
    const int lane = tid & 63;
    const int quad = lane >> 4;
    const int l16  = lane & 15;
    const int m0 = blockIdx.x * 64, n0 = blockIdx.y * 64;

    {
        const int r  = tid >> 2;
        const int c8 = (tid & 3) * 8;
        const _Float16* src = xh + (size_t)(m0 + r) * 256 + c8;
        _Float16* dst = As + r * 264 + c8;
#pragma unroll
        for (int g = 0; g < 8; ++g)
            *(f16x8*)(dst + g * 32) = *(const f16x8*)(src + g * 32);
    }
    __syncthreads();

    const int n16base = 48 + (n0 >> 4) + (w >> 1) * 2;
    const _Float16* w0p = wtp + (((size_t)(n16base + 0) * 8) << 9) + lane * 8;
    const _Float16* w1p = wtp + (((size_t)(n16base + 1) * 8) << 9) + lane * 8;
    const _Float16* arow0 = As + ((w & 1) * 32 + l16) * 264;
    const _Float16* arow1 = arow0 + 16 * 264;

    f32x4 acc[2][2];
#pragma unroll
    for (int i = 0; i < 2; ++i)
#pragma unroll
        for (int j = 0; j < 2; ++j) acc[i][j] = (f32x4){0.f, 0.f, 0.f, 0.f};

#pragma unroll
    for (int kk = 0; kk < 8; ++kk) {
        const int k8 = kk * 32 + quad * 8;
        f16x8 a0 = *(const f16x8*)(arow0 + k8);
        f16x8 a1 = *(const f16x8*)(arow1 + k8);
        f16x8 b0 = *(const f16x8*)(w0p + kk * 512);
        f16x8 b1 = *(const f16x8*)(w1p + kk * 512);
        acc[0][0] = __builtin_amdgcn_mfma_f32_16x16x32_f16(a0, b0, acc[0][0], 0, 0, 0);
        acc[0][1] = __builtin_amdgcn_mfma_f32_16x16x32_f16(a0, b1, acc[0][1], 0, 0, 0);
        acc[1][0] = __builtin_amdgcn_mfma_f32_16x16x32_f16(a1, b0, acc[1][0], 0, 0, 0);
        acc[1][1] = __builtin_amdgcn_mfma_f32_16x16x32_f16(a1, b1, acc[1][1], 0, 0, 0);
    }

#pragma unroll
    for (int i = 0; i < 2; ++i) {
        const int col = n0 + (w >> 1) * 32 + i * 16 + l16;
        const float bvv = bo[col];
#pragma unroll
        for (int jj = 0; jj < 2; ++jj) {
#pragma unroll
            for (int r = 0; r < 4; ++r) {
                const int row = m0 + (w & 1) * 32 + jj * 16 + quad * 4 + r;
                out[(size_t)row * 256 + col] = acc[jj][i][r] + bvv;
            }
        }
    }
}

// ---------------------------------------------------------------------------
// Flash attention: fragment-packed streams, transposed dataflow, fixed-max
// softmax, tab C-init bias, ones-MFMA row sums, wave-private P round-trip,
// ZERO barriers. grid 512 (XCD-swizzled), 4 waves, wave = 32 q-rows.
// ---------------------------------------------------------------------------
__global__ __launch_bounds__(256)
void attn_kernel(const _Float16* __restrict__ qs, const _Float16* __restrict__ ks,
                 const _Float16* __restrict__ vs, const float* __restrict__ tab,
                 _Float16* __restrict__ xh) {
    __shared__ __align__(16) _Float16 Ps[4][32][40];

    const int tid  = threadIdx.x;
    const int w    = tid >> 6;
    const int lane = tid & 63;
    const int quad = lane >> 4;
    const int l16  = lane & 15;

    const int n     = blockIdx.x;
    const int xcd   = n & 7;
    const int local = n >> 3;
    const int bh    = xcd * 8 + (local & 7);
    const int qc    = local >> 3;          // 0..7
    const int b = bh >> 3, h = bh & 7;
    const int qrow_base = qc * 128 + w * 32;
    const int yq = qc * 4 + w;             // q y-tile

    const _Float16* qp = qs + (((size_t)(bh * 32 + yq) * 2) << 9) + lane * 8;
    const f16x8 qf0 = *(const f16x8*)(qp);
    const f16x8 qf1 = *(const f16x8*)(qp + 512);
    const _Float16* kp = ks + (((size_t)bh * 64) << 9) + lane * 8;   // +kt*1024
    const _Float16* vp = vs + (((size_t)bh * 64) << 9) + lane * 8;
    const float* tb = tab + (((size_t)h * 63 * 3) << 8) + lane * 4;  // +dy31*768

    f16x8 ones;
#pragma unroll
    for (int j = 0; j < 8; ++j) ones[j] = (_Float16)1.0f;

    f32x4 o00 = {0.f,0.f,0.f,0.f}, o01 = {0.f,0.f,0.f,0.f};
    f32x4 o10 = {0.f,0.f,0.f,0.f}, o11 = {0.f,0.f,0.f,0.f};
    f32x4 ol0 = {0.f,0.f,0.f,0.f}, ol1 = {0.f,0.f,0.f,0.f};

    f16x8 kf0 = *(const f16x8*)(kp);
    f16x8 kf1 = *(const f16x8*)(kp + 512);
    f16x8 vf0 = *(const f16x8*)(vp);
    f16x8 vf1 = *(const f16x8*)(vp + 512);
    f32x4 c0 = *(const f32x4*)(tb + (yq + 31) * 768);
    f32x4 c1 = *(const f32x4*)(tb + (yq + 31) * 768 + 256);
    f32x4 c2 = *(const f32x4*)(tb + (yq + 31) * 768 + 512);

    for (int kt = 0; kt < 32; ++kt) {
        const bool more = (kt < 31);
        f16x8 nk0, nk1, nv0, nv1;
        f32x4 nc0, nc1, nc2;
        if (more) {
            const _Float16* kq = kp + (kt + 1) * 1024;
            nk0 = *(const f16x8*)(kq);
            nk1 = *(const f16x8*)(kq + 512);
            const _Float16* vq = vp + (kt + 1) * 1024;
            nv0 = *(const f16x8*)(vq);
            nv1 = *(const f16x8*)(vq + 512);
            const int d = (yq + 30 - kt) * 768;
            nc0 = *(const f32x4*)(tb + d);
            nc1 = *(const f32x4*)(tb + d + 256);
            nc2 = *(const f32x4*)(tb + d + 512);
        }

        // S^T = K.Q^T with bias C-init (rows = keys, cols = q)
        f32x4 s00 = __builtin_amdgcn_mfma_f32_16x16x32_f16(kf0, qf0, c1, 0, 0, 0);
        f32x4 s01 = __builtin_amdgcn_mfma_f32_16x16x32_f16(kf1, qf0, c0, 0, 0, 0);
        f32x4 s10 = __builtin_amdgcn_mfma_f32_16x16x32_f16(kf0, qf1, c2, 0, 0, 0);
        f32x4 s11 = __builtin_amdgcn_mfma_f32_16x16x32_f16(kf1, qf1, c1, 0, 0, 0);

        f16x4 p;
#pragma unroll
        for (int r = 0; r < 4; ++r) p[r] = (_Float16)__builtin_amdgcn_exp2f(s00[r]);
        *(f16x4*)(&Ps[w][l16][quad * 4]) = p;
#pragma unroll
        for (int r = 0; r < 4; ++r) p[r] = (_Float16)__builtin_amdgcn_exp2f(s01[r]);
        *(f16x4*)(&Ps[w][l16][16 + quad * 4]) = p;
#pragma unroll
        for (int r = 0; r < 4; ++r) p[r] = (_Float16)__builtin_amdgcn_exp2f(s10[r]);
        *(f16x4*)(&Ps[w][16 + l16][quad * 4]) = p;
#pragma unroll
        for (int r = 0; r < 4; ++r) p[r] = (_Float16)__builtin_amdgcn_exp2f(s11[r]);
        *(f16x4*)(&Ps[w][16 + l16][16 + quad * 4]) = p;

        const f16x8 pf0 = *(const f16x8*)(&Ps[w][l16][quad * 8]);
        const f16x8 pf1 = *(const f16x8*)(&Ps[w][16 + l16][quad * 8]);
        o00 = __builtin_amdgcn_mfma_f32_16x16x32_f16(vf0, pf0, o00, 0, 0, 0);
        o01 = __builtin_amdgcn_mfma_f32_16x16x32_f16(vf0, pf1, o01, 0, 0, 0);
        o10 = __builtin_amdgcn_mfma_f32_16x16x32_f16(vf1, pf0, o10, 0, 0, 0);
        o11 = __builtin_amdgcn_mfma_f32_16x16x32_f16(vf1, pf1, o11, 0, 0, 0);
        ol0 = __builtin_amdgcn_mfma_f32_16x16x32_f16(ones, pf0, ol0, 0, 0, 0);
        ol1 = __builtin_amdgcn_mfma_f32_16x16x32_f16(ones, pf1, ol1, 0, 0, 0);

        if (more) {
            kf0 = nk0; kf1 = nk1; vf0 = nv0; vf1 = nv1;
            c0 = nc0; c1 = nc1; c2 = nc2;
        }
    }

    // epilogue: normalize, store xh row-major fp16
#pragma unroll
    for (int qh = 0; qh < 2; ++qh) {
        const f32x4 onl = qh ? o01 : o00;   // hd 0-15
        const f32x4 onh = qh ? o11 : o10;   // hd 16-31
        const f32x4 ll  = qh ? ol1 : ol0;
        const float inv = __builtin_amdgcn_rcpf(ll[0]);
        const int qg = qrow_base + qh * 16 + l16;
        f16x4 u, v;
#pragma unroll
        for (int r = 0; r < 4; ++r) {
            u[r] = (_Float16)(onl[r] * inv);
            v[r] = (_Float16)(onh[r] * inv);
        }
        _Float16* op = xh + ((size_t)(b * S_LEN + qg)) * D_MOD + h * 32 + quad * 4;
        *(f16x4*)(op)      = u;
        *(f16x4*)(op + 16) = v;
    }
}

// ---------------------------------------------------------------------------
extern "C" void kernel_launch(void* const* d_in, const int* in_sizes, int n_in,
                              void* d_out, int out_size, void* d_ws, size_t ws_size,
                              hipStream_t stream) {
    const float* in_q  = (const float*)d_in[0];
    const float* in_kv = (const float*)d_in[1];
    const float* Wq    = (const float*)d_in[2];
    const float* bq    = (const float*)d_in[3];
    const float* Wk    = (const float*)d_in[4];
    const float* bk    = (const float*)d_in[5];
    const float* Wv    = (const float*)d_in[6];
    const float* bv    = (const float*)d_in[7];
    const float* rel   = (const float*)d_in[8];
    const float* Wo    = (const float*)d_in[9];
    const float* bo    = (const float*)d_in[10];
    float* out = (float*)d_out;

    char* wsb = (char*)d_ws;
    _Float16* qs  = (_Float16*)(wsb);                         // 4 MB packed Q
    _Float16* ks  = (_Float16*)(wsb + (size_t)4  * 1048576);  // 4 MB packed K
    _Float16* vs  = (_Float16*)(wsb + (size_t)8  * 1048576);  // 4 MB packed V^T
    _Float16* xh  = (_Float16*)(wsb + (size_t)12 * 1048576);  // 4 MB row-major
    _Float16* wtp = (_Float16*)(wsb + (size_t)16 * 1048576);  // 512 KB packed W
    float*    tab = (float*)   (wsb + (size_t)17 * 1048576);  // 1.55 MB bias tab

    const dim3 blk(256);

    prep_kernel<<<dim3(95), blk, 0, stream>>>(Wq, Wk, Wv, Wo, rel, wtp, tab);
    gemm_qkv_kernel<<<dim3(128, 4, 2), blk, 0, stream>>>(
        in_q, in_kv, wtp, bq, bk, bv, qs, ks, vs);
    attn_kernel<<<dim3(512), blk, 0, stream>>>(qs, ks, vs, tab, xh);
    gemm_out_kernel<<<dim3(128, 4), blk, 0, stream>>>(xh, wtp, bo, out);
}